// Round 15
// baseline (83.040 us; speedup 1.0000x reference)
//
#include <hip/hip_runtime.h>
#include <math.h>

#define EMBED 1024
#define NHEAD 8
#define HDIM 128
#define TK 255
#define BATCH 4
#define LQ 128
#define BH 32

typedef __attribute__((ext_vector_type(4))) float f32x4;
typedef __attribute__((ext_vector_type(8))) short short8;
typedef __attribute__((ext_vector_type(4))) short short4v;

static __device__ __forceinline__ unsigned short f2bf(float f) {
    unsigned u = __float_as_uint(f);
    u += 0x7FFFu + ((u >> 16) & 1u);
    return (unsigned short)(u >> 16);
}
static __device__ __forceinline__ float bfbits2f(unsigned short s) {
    return __uint_as_float(((unsigned)s) << 16);
}

// ============ prep: (blocks 0..127) suffix-scan keys -> packed apk rows 512..1535
//              (blocks 128..2175) pack query/value/weights -> apk / wpk
__global__ __launch_bounds__(256) void prep_kernel(
    const float* __restrict__ query, const float* __restrict__ key_t,
    const float* __restrict__ value, const float* __restrict__ ipw,
    const float* __restrict__ opw,
    unsigned short* __restrict__ apk, unsigned short* __restrict__ wpk)
{
    const int blk = blockIdx.x;
    const int t = threadIdx.x;
    if (blk < 128) {
        const int b = blk >> 5, eg = blk & 31;
        const int cl = t & 31, seg = t >> 5;
        const int e = eg * 32 + cl;
        __shared__ float tot[8][33];
        float vals[32];
        float acc = 0.f;
        const int nhi = seg * 32 + 31;
        #pragma unroll
        for (int i = 0; i < 32; ++i) {
            const int n = nhi - i;
            float v = 0.f;
            if (n < TK) v = key_t[(long)(n * 4 + b) * 1024 + e];
            acc += v;
            vals[i] = acc;
        }
        tot[seg][cl] = acc;
        __syncthreads();
        float add = 0.f;
        #pragma unroll
        for (int s = 0; s < 8; ++s) if (s > seg) add += tot[s][cl];
        #pragma unroll
        for (int i = 0; i < 32; ++i) {
            const int n = nhi - i;
            const float f = vals[i] + add;
            const unsigned short hv = f2bf(f);
            const unsigned short lv = f2bf(f - bfbits2f(hv));
            unsigned short* dst = apk + (long)(512 + b * 256 + n) * 2048 + e;
            dst[0] = hv;
            dst[1024] = lv;
        }
    } else {
        const int APKC = 1536 * 256;
        const int TOT = APKC + 4096 * 256;
        for (int idx = (blk - 128) * 256 + t; idx < TOT; idx += 2048 * 256) {
            const bool isA = idx < APKC;
            const int rel = isA ? idx : idx - APKC;
            const int row = rel >> 8, c4 = rel & 255;
            const float* src = nullptr; long srow = 0;
            unsigned short* dst;
            bool wlo = true;
            if (isA) {
                if (row < 512) { src = query; srow = row; dst = apk + (long)row * 2048; }
                else {
                    const int vr = row - 512;
                    dst = apk + (long)(1536 + vr) * 2048;
                    if (vr < 1020) { src = value; srow = vr; }
                }
            } else {
                dst = wpk + (long)row * 2048;
                if (row < 3072) { src = ipw; srow = row; }
                else { src = opw; srow = row - 3072; }
                wlo = (row < 2048);
            }
            float4 f = make_float4(0.f, 0.f, 0.f, 0.f);
            if (src) f = *(const float4*)(src + srow * 1024 + c4 * 4);
            const unsigned short h0 = f2bf(f.x), h1 = f2bf(f.y), h2 = f2bf(f.z), h3 = f2bf(f.w);
            short4v hv;
            hv[0] = (short)h0; hv[1] = (short)h1; hv[2] = (short)h2; hv[3] = (short)h3;
            *(short4v*)(dst + c4 * 4) = hv;
            if (wlo) {
                short4v lv;
                lv[0] = (short)f2bf(f.x - bfbits2f(h0));
                lv[1] = (short)f2bf(f.y - bfbits2f(h1));
                lv[2] = (short)f2bf(f.z - bfbits2f(h2));
                lv[3] = (short)f2bf(f.w - bfbits2f(h3));
                *(short4v*)(dst + 1024 + c4 * 4) = lv;
            }
        }
    }
}

// ============ bgemm3: global_load_lds staging (width=16), double-buffered LDS ============
// LDS contents identical to bgemm2: swizzle applied via pre-swizzled GLOBAL source
// (unit = (lane&7)^(row&7)), linear LDS dest (HW: base + lane*16). Rule #21 compliant.
// EPI 0: fp32 C=(acc+bias)*scale. EPI 1: fp32 C=acc+(255-(m&255))*bias.
// EPI 2: packed bf16 hi/lo (ld 2048). EPI 3: bf16 hi only (ld 1024).
template<int BM, int BN, int TERMS, int EPI>
__device__ __forceinline__ void bgemm3(
    const unsigned short* __restrict__ A,
    const unsigned short* __restrict__ B,
    const float* __restrict__ bias,
    void* __restrict__ Cv, long ldc, float scale,
    int m0, int n0, unsigned char* lds)
{
    constexpr int AH = 0;
    constexpr int AL = BM * 128;
    constexpr int BHo = 2 * BM * 128;
    constexpr int BLo = BHo + BN * 128;
    constexpr int BUFSZ = 2 * BM * 128 + 2 * BN * 128;
    constexpr int FM2 = BM / 32, FN2 = BN / 32;
    constexpr int GA = BM / 8, GB = BN / 8;              // 1KB issue-groups per plane
    constexpr int NI = 2 * GA + (TERMS == 3 ? 2 * GB : GB);
    constexpr int IPW = NI / 4;                          // issues per wave
    const int t = threadIdx.x, lane = t & 63, wave = t >> 6;
    const int wm = wave >> 1, wn = wave & 1;

    f32x4 acc[FM2][FN2];
    #pragma unroll
    for (int i = 0; i < FM2; ++i)
        #pragma unroll
        for (int j = 0; j < FN2; ++j)
            #pragma unroll
            for (int e = 0; e < 4; ++e) acc[i][j][e] = 0.f;

    const int l8 = lane >> 3, lu = lane & 7;

    // stage one K-step's planes into buffer at bufoff via global_load_lds
    auto stage = [&](int kt, int bufoff) {
        #pragma unroll
        for (int j = 0; j < IPW; ++j) {
            const int q = wave * IPW + j;
            const unsigned short* src; int srcoff, ldsoff, grp, rowbase;
            if (q < GA)              { src = A; srcoff = 0;    ldsoff = AH;  grp = q;               rowbase = m0; }
            else if (q < 2 * GA)     { src = A; srcoff = 1024; ldsoff = AL;  grp = q - GA;          rowbase = m0; }
            else if (q < 2 * GA + GB){ src = B; srcoff = 0;    ldsoff = BHo; grp = q - 2 * GA;      rowbase = n0; }
            else                     { src = B; srcoff = 1024; ldsoff = BLo; grp = q - 2 * GA - GB; rowbase = n0; }
            const int rl = grp * 8 + l8;                 // tile-local row
            const long gidx = (long)(rowbase + rl) * 2048 + srcoff + kt * 64 + ((lu ^ (rl & 7)) << 3);
            __builtin_amdgcn_global_load_lds(
                (const __attribute__((address_space(1))) void*)(src + gidx),
                (__attribute__((address_space(3))) void*)(lds + bufoff + ldsoff + grp * 1024),
                16, 0, 0);
        }
    };

    stage(0, 0);
    __syncthreads();

    for (int kt = 0; kt < 16; ++kt) {
        const int cur = (kt & 1) * BUFSZ;
        if (kt + 1 < 16) stage(kt + 1, ((kt + 1) & 1) * BUFSZ);
        #pragma unroll
        for (int ks = 0; ks < 2; ++ks) {
            short8 afh[FM2], afl[FM2], bgh[FN2], bgl[FN2];
            #pragma unroll
            for (int fm = 0; fm < FM2; ++fm) {
                const int row = wm * (BM / 2) + fm * 16 + (lane & 15);
                const int byte = row * 128 + (((ks * 4 + (lane >> 4)) ^ (row & 7)) << 4);
                afh[fm] = *(const short8*)(lds + cur + AH + byte);
                afl[fm] = *(const short8*)(lds + cur + AL + byte);
            }
            #pragma unroll
            for (int fn = 0; fn < FN2; ++fn) {
                const int row = wn * (BN / 2) + fn * 16 + (lane & 15);
                const int byte = row * 128 + (((ks * 4 + (lane >> 4)) ^ (row & 7)) << 4);
                bgh[fn] = *(const short8*)(lds + cur + BHo + byte);
                if (TERMS == 3) bgl[fn] = *(const short8*)(lds + cur + BLo + byte);
            }
            #pragma unroll
            for (int fm = 0; fm < FM2; ++fm)
                #pragma unroll
                for (int fn = 0; fn < FN2; ++fn) {
                    acc[fm][fn] = __builtin_amdgcn_mfma_f32_16x16x32_bf16(afh[fm], bgh[fn], acc[fm][fn], 0, 0, 0);
                    acc[fm][fn] = __builtin_amdgcn_mfma_f32_16x16x32_bf16(afl[fm], bgh[fn], acc[fm][fn], 0, 0, 0);
                    if (TERMS == 3)
                        acc[fm][fn] = __builtin_amdgcn_mfma_f32_16x16x32_bf16(afh[fm], bgl[fn], acc[fm][fn], 0, 0, 0);
                }
        }
        __syncthreads();
    }

    #pragma unroll
    for (int fm = 0; fm < FM2; ++fm)
        #pragma unroll
        for (int i = 0; i < 4; ++i) {
            const int m = m0 + wm * (BM / 2) + fm * 16 + ((lane >> 4) << 2) + i;
            #pragma unroll
            for (int fn = 0; fn < FN2; ++fn) {
                const int n = n0 + wn * (BN / 2) + fn * 16 + (lane & 15);
                float v = acc[fm][fn][i];
                if (EPI == 0) {
                    float* C = (float*)Cv;
                    if (bias) v += bias[n];
                    C[(long)m * ldc + n] = v * scale;
                } else if (EPI == 1) {
                    float* C = (float*)Cv;
                    v += (float)(255 - (m & 255)) * bias[n];
                    C[(long)m * ldc + n] = v;
                } else if (EPI == 2) {
                    unsigned short* C = (unsigned short*)Cv;
                    const float val = (v + bias[n]) * scale;
                    const unsigned short hv = f2bf(val);
                    const unsigned short lv = f2bf(val - bfbits2f(hv));
                    C[(long)m * 2048 + n] = hv;
                    C[(long)m * 2048 + 1024 + n] = lv;
                } else {
                    unsigned short* C = (unsigned short*)Cv;
                    const float val = v + bias[n];
                    C[(long)m * 1024 + n] = f2bf(val);
                }
            }
        }
}

// ---- fused q/k(suffix)/v projections, 64x64 tiles, XCD-swizzled. grid (16, 40)
__global__ __launch_bounds__(256) void qkvb_kernel(
    const unsigned short* __restrict__ apk, const unsigned short* __restrict__ wpk,
    const float* __restrict__ ipb,
    unsigned short* __restrict__ qpk, float* __restrict__ sbuf,
    unsigned short* __restrict__ vpk, float qscale)
{
    __shared__ __align__(16) unsigned char lds[2 * (4 * 64 * 128)];   // 64 KB dbuf
    const int lid = blockIdx.y * 16 + blockIdx.x;
    const int xcd = lid & 7, slot = lid >> 3;        // slot in [0,80)
    const int y = xcd * 5 + (slot >> 4);
    const int x = slot & 15;
    if (y < 8) {
        bgemm3<64, 64, 3, 2>(apk, wpk, ipb, qpk, 2048, qscale,
                             y * 64, x * 64, lds);
    } else if (y < 24) {
        bgemm3<64, 64, 3, 1>(apk + 512L * 2048, wpk + 1024L * 2048, ipb + 1024, sbuf, 1024, 1.f,
                             (y - 8) * 64, x * 64, lds);
    } else {
        bgemm3<64, 64, 2, 3>(apk + 1536L * 2048, wpk + 2048L * 2048, ipb + 2048, vpk, 1024, 1.f,
                             (y - 24) * 64, x * 64, lds);
    }
}

// ---- out projection, 32x64 tiles, 2-term, XCD-swizzled. grid 256
__global__ __launch_bounds__(256) void outprojb_kernel(
    const unsigned short* __restrict__ apk2, const unsigned short* __restrict__ wpk,
    const float* __restrict__ opb, float* __restrict__ out)
{
    __shared__ __align__(16) unsigned char lds[2 * (2 * 32 * 128 + 2 * 64 * 128)];  // 48 KB dbuf
    const int lid = blockIdx.x;
    const int xcd = lid & 7, slot = lid >> 3;        // slot in [0,32)
    const int y = xcd * 2 + (slot >> 4);
    const int x = slot & 15;
    bgemm3<32, 64, 2, 0>(apk2, wpk + 3072L * 2048, opb, out, 1024, 1.f,
                         y * 32, x * 64, lds);
}

// ============ fused attention, 8-way q split (16 q-rows/block), 2 blocks/CU. grid 256 ====
// LDS: QH 4K | QL 4K | KH 16K (Vt overlay) | KL 16K | PH 8K | RED 512B | INV 64B
#define F_QH 0
#define F_QL 4096
#define F_KH 8192
#define F_KL 24576
#define F_PH 40960
#define F_RED 49152
#define F_INV 49664

__global__ __launch_bounds__(256, 2) void fused_attn_kernel(
    const unsigned short* __restrict__ qpk, const float* __restrict__ sbuf,
    const unsigned short* __restrict__ vpk, const int* __restrict__ indices,
    unsigned short* __restrict__ apk2)
{
    __shared__ __align__(16) unsigned char lds[49728];
    __shared__ int onode[256];
    const int lid = blockIdx.x;
    const int xcd = lid & 7, slot = lid >> 3;        // slot in [0,32)
    const int bh = xcd * 4 + (slot >> 3), qq8 = slot & 7;
    const int b = bh >> 3, h = bh & 7;
    const int t = threadIdx.x, lane = t & 63, wn = t >> 6;
    float* red = (float*)(lds + F_RED);
    float* inv = (float*)(lds + F_INV);

    if (t < TK) {
        const int r0 = indices[(b * TK + t) * 2 + 0];
        const int c0 = indices[(b * TK + t) * 2 + 1];
        onode[t] = t + 2 * (c0 - r0) + 1;
    } else if (t < 256) {
        onode[t] = 255;
    }

    {
        #pragma unroll
        for (int rr = 0; rr < 2; ++rr) {
            const int chunk = rr * 256 + t;
            const int row = chunk >> 5;
            const int rem = chunk & 31;
            const int plane = rem >> 4, u = rem & 15;
            const int tq = qq8 * 16 + row;
            short8 v = *(const short8*)(qpk + (long)(tq * 4 + b) * 2048 + plane * 1024 + h * 128 + u * 8);
            const int byte = row * 256 + ((u ^ (row & 15)) << 4);
            *(short8*)(lds + (plane ? F_QL : F_QH) + byte) = v;
        }
    }

    f32x4 acc[4];
    #pragma unroll
    for (int nb = 0; nb < 4; ++nb)
        #pragma unroll
        for (int e = 0; e < 4; ++e) acc[nb][e] = 0.f;

    #pragma unroll
    for (int nb = 0; nb < 4; ++nb) {
        __syncthreads();
        {
            const int c4 = t & 31, r8 = t >> 5;
            const float* sb = sbuf + (long)b * 256 * 1024 + h * 128 + c4 * 4;
            #pragma unroll
            for (int rr = 0; rr < 8; ++rr) {
                const int nl = r8 + rr * 8;
                const int node = nb * 64 + nl;
                float4 f0 = *(const float4*)(sb + (long)node * 1024);
                float4 f1 = *(const float4*)(sb + (long)onode[node] * 1024);
                float4 f = make_float4(f0.x - f1.x, f0.y - f1.y, f0.z - f1.z, f0.w - f1.w);
                const unsigned short h0 = f2bf(f.x), h1 = f2bf(f.y), h2 = f2bf(f.z), h3 = f2bf(f.w);
                short4v hv, lv;
                hv[0] = (short)h0; hv[1] = (short)h1; hv[2] = (short)h2; hv[3] = (short)h3;
                lv[0] = (short)f2bf(f.x - bfbits2f(h0));
                lv[1] = (short)f2bf(f.y - bfbits2f(h1));
                lv[2] = (short)f2bf(f.z - bfbits2f(h2));
                lv[3] = (short)f2bf(f.w - bfbits2f(h3));
                const int byte = nl * 256 + ((((c4 >> 1) ^ (nl & 15)) << 4) | ((c4 & 1) << 3));
                *(short4v*)(lds + F_KH + byte) = hv;
                *(short4v*)(lds + F_KL + byte) = lv;
            }
        }
        __syncthreads();
        #pragma unroll
        for (int ks = 0; ks < 4; ++ks) {
            short8 ah, al, bh_, bl;
            {
                const int row = lane & 15;
                const int byte = row * 256 + (((ks * 4 + (lane >> 4)) ^ (row & 15)) << 4);
                ah = *(const short8*)(lds + F_QH + byte);
                al = *(const short8*)(lds + F_QL + byte);
            }
            {
                const int rown = wn * 16 + (lane & 15);
                const int byte = rown * 256 + (((ks * 4 + (lane >> 4)) ^ (rown & 15)) << 4);
                bh_ = *(const short8*)(lds + F_KH + byte);
                bl = *(const short8*)(lds + F_KL + byte);
            }
            acc[nb] = __builtin_amdgcn_mfma_f32_16x16x32_bf16(ah, bh_, acc[nb], 0, 0, 0);
            acc[nb] = __builtin_amdgcn_mfma_f32_16x16x32_bf16(al, bh_, acc[nb], 0, 0, 0);
            acc[nb] = __builtin_amdgcn_mfma_f32_16x16x32_bf16(ah, bl, acc[nb], 0, 0, 0);
        }
    }

    float pmax[4] = {-1e30f, -1e30f, -1e30f, -1e30f};
    #pragma unroll
    for (int nb = 0; nb < 4; ++nb)
        #pragma unroll
        for (int i = 0; i < 4; ++i) {
            const int col = nb * 64 + wn * 16 + (lane & 15);
            const float s = (col < TK) ? acc[nb][i] : -1e30f;
            pmax[i] = fmaxf(pmax[i], s);
        }
    #pragma unroll
    for (int off = 1; off < 16; off <<= 1)
        #pragma unroll
        for (int i = 0; i < 4; ++i) pmax[i] = fmaxf(pmax[i], __shfl_xor(pmax[i], off));
    if ((lane & 15) == 0) {
        #pragma unroll
        for (int i = 0; i < 4; ++i) {
            const int row = ((lane >> 4) << 2) + i;
            red[wn * 16 + row] = pmax[i];
        }
    }
    __syncthreads();
    float rm[4];
    #pragma unroll
    for (int i = 0; i < 4; ++i) {
        const int row = ((lane >> 4) << 2) + i;
        rm[i] = fmaxf(fmaxf(red[row], red[16 + row]), fmaxf(red[32 + row], red[48 + row]));
    }
    float psum[4] = {0.f, 0.f, 0.f, 0.f};
    #pragma unroll
    for (int nb = 0; nb < 4; ++nb)
        #pragma unroll
        for (int i = 0; i < 4; ++i) {
            const int col = nb * 64 + wn * 16 + (lane & 15);
            const int row = ((lane >> 4) << 2) + i;
            float p = 0.f;
            if (col < TK) p = __expf(acc[nb][i] - rm[i]);
            psum[i] += p;
            const unsigned short hp = f2bf(p);
            const int u = ((col >> 3) ^ ((row & 15) << 1));
            const int byte = row * 512 + (u << 4) + (col & 7) * 2;
            *(unsigned short*)(lds + F_PH + byte) = hp;
        }
    #pragma unroll
    for (int off = 1; off < 16; off <<= 1)
        #pragma unroll
        for (int i = 0; i < 4; ++i) psum[i] += __shfl_xor(psum[i], off);
    if ((lane & 15) == 0) {
        #pragma unroll
        for (int i = 0; i < 4; ++i) {
            const int row = ((lane >> 4) << 2) + i;
            red[64 + wn * 16 + row] = psum[i];
        }
    }
    __syncthreads();
    if (wn == 0 && (lane & 15) == 0) {
        #pragma unroll
        for (int i = 0; i < 4; ++i) {
            const int row = ((lane >> 4) << 2) + i;
            inv[row] = 1.f / (red[64 + row] + red[80 + row] + red[96 + row] + red[112 + row]);
        }
    }

    f32x4 accO[2];
    #pragma unroll
    for (int fn = 0; fn < 2; ++fn)
        #pragma unroll
        for (int e = 0; e < 4; ++e) accO[fn][e] = 0.f;

    #pragma unroll
    for (int nb = 0; nb < 4; ++nb) {
        __syncthreads();
        {
            const int c8 = t & 15, r16 = t >> 4;
            #pragma unroll
            for (int rr = 0; rr < 4; ++rr) {
                const int nl = r16 + rr * 16;
                const int node = nb * 64 + nl;
                short8 v = {0, 0, 0, 0, 0, 0, 0, 0};
                if (node < TK) v = *(const short8*)(vpk + (long)(node * 4 + b) * 1024 + h * 128 + c8 * 8);
                #pragma unroll
                for (int j = 0; j < 8; ++j) {
                    const int d = c8 * 8 + j;
                    const int byte = d * 128 + ((((nl >> 3) ^ (d & 7)) << 4) | ((nl & 7) << 1));
                    *(unsigned short*)(lds + F_KH + byte) = (unsigned short)v[j];
                }
            }
        }
        __syncthreads();
        #pragma unroll
        for (int ks = 0; ks < 2; ++ks) {
            short8 pa, vb[2];
            {
                const int row = lane & 15;
                const int u = (nb * 8 + ks * 4 + (lane >> 4)) ^ ((row & 15) << 1);
                const int byte = row * 512 + (u << 4);
                pa = *(const short8*)(lds + F_PH + byte);
            }
            #pragma unroll
            for (int fn = 0; fn < 2; ++fn) {
                const int d = wn * 32 + fn * 16 + (lane & 15);
                const int u = (ks * 4 + (lane >> 4)) ^ (d & 7);
                const int byte = d * 128 + (u << 4);
                vb[fn] = *(const short8*)(lds + F_KH + byte);
            }
            #pragma unroll
            for (int fn = 0; fn < 2; ++fn)
                accO[fn] = __builtin_amdgcn_mfma_f32_16x16x32_bf16(pa, vb[fn], accO[fn], 0, 0, 0);
        }
    }

    __syncthreads();
    #pragma unroll
    for (int i = 0; i < 4; ++i) {
        const int row = ((lane >> 4) << 2) + i;
        const float iv = inv[row];
        const int arow = (qq8 * 16 + row) * 4 + b;
        #pragma unroll
        for (int fn = 0; fn < 2; ++fn) {
            const int col = h * 128 + wn * 32 + fn * 16 + (lane & 15);
            const float val = accO[fn][i] * iv;
            const unsigned short hv = f2bf(val);
            const unsigned short lv = f2bf(val - bfbits2f(hv));
            apk2[(long)arow * 2048 + col] = hv;
            apk2[(long)arow * 2048 + 1024 + col] = lv;
        }
    }
}

extern "C" void kernel_launch(void* const* d_in, const int* in_sizes, int n_in,
                              void* d_out, int out_size, void* d_ws, size_t ws_size,
                              hipStream_t stream) {
    const float* query   = (const float*)d_in[0];
    const float* key_t   = (const float*)d_in[1];
    const float* value   = (const float*)d_in[2];
    const int*   indices = (const int*)d_in[3];
    const float* ipw     = (const float*)d_in[4];
    const float* ipb     = (const float*)d_in[5];
    const float* opw     = (const float*)d_in[6];
    const float* opb     = (const float*)d_in[7];
    float* out = (float*)d_out;

    float* ws = (float*)d_ws;
    float* sbuf = ws;                                          // [1024][1024] fp32 (4 MB)
    unsigned short* qpk = (unsigned short*)(sbuf + 1048576);   // [512][2048] bf16 hi/lo
    unsigned short* vpk = qpk + 512L * 2048;                   // [1024][1024] bf16 hi
    unsigned short* apk = vpk + 1024L * 1024;                  // [2560][2048]
    unsigned short* wpk = apk + 2560L * 2048;                  // [4096][2048]
    unsigned short* apk2 = apk;                                // overlay (apk dead after qkvb)

    const float qscale = 0.08838834764831843f;  // 128^-0.5

    prep_kernel<<<dim3(2176), 256, 0, stream>>>(query, key_t, value, ipw, opw, apk, wpk);

    qkvb_kernel<<<dim3(16, 40), 256, 0, stream>>>(apk, wpk, ipb, qpk, sbuf, vpk, qscale);

    fused_attn_kernel<<<dim3(256), 256, 0, stream>>>(qpk, sbuf, vpk, indices, apk2);

    outprojb_kernel<<<dim3(256), 256, 0, stream>>>(apk2, wpk, opb, out);
}

// Round 16
// 69.814 us; speedup vs baseline: 1.1894x; 1.1894x over previous
//
#include <hip/hip_runtime.h>
#include <math.h>

#define EMBED 1024
#define NHEAD 8
#define HDIM 128
#define TK 255
#define BATCH 4
#define LQ 128
#define BH 32

typedef __attribute__((ext_vector_type(4))) float f32x4;
typedef __attribute__((ext_vector_type(8))) short short8;
typedef __attribute__((ext_vector_type(4))) short short4v;

static __device__ __forceinline__ unsigned short f2bf(float f) {
    unsigned u = __float_as_uint(f);
    u += 0x7FFFu + ((u >> 16) & 1u);
    return (unsigned short)(u >> 16);
}
static __device__ __forceinline__ float bfbits2f(unsigned short s) {
    return __uint_as_float(((unsigned)s) << 16);
}

// ============ prep: (blocks 0..127) suffix-scan keys -> packed apk rows 512..1535
//              (blocks 128..2175) pack query/value/weights -> apk / wpk
__global__ __launch_bounds__(256) void prep_kernel(
    const float* __restrict__ query, const float* __restrict__ key_t,
    const float* __restrict__ value, const float* __restrict__ ipw,
    const float* __restrict__ opw,
    unsigned short* __restrict__ apk, unsigned short* __restrict__ wpk)
{
    const int blk = blockIdx.x;
    const int t = threadIdx.x;
    if (blk < 128) {
        const int b = blk >> 5, eg = blk & 31;
        const int cl = t & 31, seg = t >> 5;
        const int e = eg * 32 + cl;
        __shared__ float tot[8][33];
        float vals[32];
        float acc = 0.f;
        const int nhi = seg * 32 + 31;
        #pragma unroll
        for (int i = 0; i < 32; ++i) {
            const int n = nhi - i;
            float v = 0.f;
            if (n < TK) v = key_t[(long)(n * 4 + b) * 1024 + e];
            acc += v;
            vals[i] = acc;
        }
        tot[seg][cl] = acc;
        __syncthreads();
        float add = 0.f;
        #pragma unroll
        for (int s = 0; s < 8; ++s) if (s > seg) add += tot[s][cl];
        #pragma unroll
        for (int i = 0; i < 32; ++i) {
            const int n = nhi - i;
            const float f = vals[i] + add;
            const unsigned short hv = f2bf(f);
            const unsigned short lv = f2bf(f - bfbits2f(hv));
            unsigned short* dst = apk + (long)(512 + b * 256 + n) * 2048 + e;
            dst[0] = hv;
            dst[1024] = lv;
        }
    } else {
        const int APKC = 1536 * 256;
        const int TOT = APKC + 4096 * 256;
        for (int idx = (blk - 128) * 256 + t; idx < TOT; idx += 2048 * 256) {
            const bool isA = idx < APKC;
            const int rel = isA ? idx : idx - APKC;
            const int row = rel >> 8, c4 = rel & 255;
            const float* src = nullptr; long srow = 0;
            unsigned short* dst;
            bool wlo = true;
            if (isA) {
                if (row < 512) { src = query; srow = row; dst = apk + (long)row * 2048; }
                else {
                    const int vr = row - 512;
                    dst = apk + (long)(1536 + vr) * 2048;
                    if (vr < 1020) { src = value; srow = vr; }
                }
            } else {
                dst = wpk + (long)row * 2048;
                if (row < 3072) { src = ipw; srow = row; }
                else { src = opw; srow = row - 3072; }
                wlo = (row < 2048);
            }
            float4 f = make_float4(0.f, 0.f, 0.f, 0.f);
            if (src) f = *(const float4*)(src + srow * 1024 + c4 * 4);
            const unsigned short h0 = f2bf(f.x), h1 = f2bf(f.y), h2 = f2bf(f.z), h3 = f2bf(f.w);
            short4v hv;
            hv[0] = (short)h0; hv[1] = (short)h1; hv[2] = (short)h2; hv[3] = (short)h3;
            *(short4v*)(dst + c4 * 4) = hv;
            if (wlo) {
                short4v lv;
                lv[0] = (short)f2bf(f.x - bfbits2f(h0));
                lv[1] = (short)f2bf(f.y - bfbits2f(h1));
                lv[2] = (short)f2bf(f.z - bfbits2f(h2));
                lv[3] = (short)f2bf(f.w - bfbits2f(h3));
                *(short4v*)(dst + 1024 + c4 * 4) = lv;
            }
        }
    }
}

// ============ bgemm2: all-plane BK=64 staging, TERMS MFMAs per fragment pair ============
// EPI 0: fp32 C = (acc + bias)*scale.   EPI 1: fp32 C = acc + (255-(m&255))*bias.
// EPI 2: packed bf16 hi/lo (ld 2048), (acc+bias)*scale.  EPI 3: bf16 hi only (ld 1024), acc+bias.
template<int BM, int BN, int TERMS, int EPI>
__device__ __forceinline__ void bgemm2(
    const unsigned short* __restrict__ A,
    const unsigned short* __restrict__ B,
    const float* __restrict__ bias,
    void* __restrict__ Cv, long ldc, float scale,
    int m0, int n0, unsigned char* lds)
{
    constexpr int AH = 0;
    constexpr int AL = BM * 128;
    constexpr int BHo = 2 * BM * 128;
    constexpr int BLo = BHo + BN * 128;
    constexpr int FM2 = BM / 32, FN2 = BN / 32;
    constexpr int CA = BM / 32;
    constexpr int CB = BN / 32;
    const int t = threadIdx.x, lane = t & 63, wave = t >> 6;
    const int wm = wave >> 1, wn = wave & 1;

    f32x4 acc[FM2][FN2];
    #pragma unroll
    for (int i = 0; i < FM2; ++i)
        #pragma unroll
        for (int j = 0; j < FN2; ++j)
            #pragma unroll
            for (int e = 0; e < 4; ++e) acc[i][j][e] = 0.f;

    const int srow_a = t >> 3, su = t & 7;
    short8 rah[CA], ral[CA], rbh[CB], rbl[CB];

    #pragma unroll
    for (int c = 0; c < CA; ++c) {
        const long base = (long)(m0 + c * 32 + srow_a) * 2048 + su * 8;
        rah[c] = *(const short8*)(A + base);
        ral[c] = *(const short8*)(A + base + 1024);
    }
    #pragma unroll
    for (int c = 0; c < CB; ++c) {
        const long base = (long)(n0 + c * 32 + srow_a) * 2048 + su * 8;
        rbh[c] = *(const short8*)(B + base);
        if (TERMS == 3) rbl[c] = *(const short8*)(B + base + 1024);
    }

    for (int kt = 0; kt < 16; ++kt) {
        #pragma unroll
        for (int c = 0; c < CA; ++c) {
            const int row = c * 32 + srow_a;
            const int byte = row * 128 + ((su ^ (row & 7)) << 4);
            *(short8*)(lds + AH + byte) = rah[c];
            *(short8*)(lds + AL + byte) = ral[c];
        }
        #pragma unroll
        for (int c = 0; c < CB; ++c) {
            const int row = c * 32 + srow_a;
            const int byte = row * 128 + ((su ^ (row & 7)) << 4);
            *(short8*)(lds + BHo + byte) = rbh[c];
            if (TERMS == 3) *(short8*)(lds + BLo + byte) = rbl[c];
        }
        __syncthreads();
        if (kt + 1 < 16) {
            const int off = (kt + 1) * 64;
            #pragma unroll
            for (int c = 0; c < CA; ++c) {
                const long base = (long)(m0 + c * 32 + srow_a) * 2048 + off + su * 8;
                rah[c] = *(const short8*)(A + base);
                ral[c] = *(const short8*)(A + base + 1024);
            }
            #pragma unroll
            for (int c = 0; c < CB; ++c) {
                const long base = (long)(n0 + c * 32 + srow_a) * 2048 + off + su * 8;
                rbh[c] = *(const short8*)(B + base);
                if (TERMS == 3) rbl[c] = *(const short8*)(B + base + 1024);
            }
        }
        #pragma unroll
        for (int ks = 0; ks < 2; ++ks) {
            short8 afh[FM2], afl[FM2], bgh[FN2], bgl[FN2];
            #pragma unroll
            for (int fm = 0; fm < FM2; ++fm) {
                const int row = wm * (BM / 2) + fm * 16 + (lane & 15);
                const int byte = row * 128 + (((ks * 4 + (lane >> 4)) ^ (row & 7)) << 4);
                afh[fm] = *(const short8*)(lds + AH + byte);
                afl[fm] = *(const short8*)(lds + AL + byte);
            }
            #pragma unroll
            for (int fn = 0; fn < FN2; ++fn) {
                const int row = wn * (BN / 2) + fn * 16 + (lane & 15);
                const int byte = row * 128 + (((ks * 4 + (lane >> 4)) ^ (row & 7)) << 4);
                bgh[fn] = *(const short8*)(lds + BHo + byte);
                if (TERMS == 3) bgl[fn] = *(const short8*)(lds + BLo + byte);
            }
            #pragma unroll
            for (int fm = 0; fm < FM2; ++fm)
                #pragma unroll
                for (int fn = 0; fn < FN2; ++fn) {
                    acc[fm][fn] = __builtin_amdgcn_mfma_f32_16x16x32_bf16(afh[fm], bgh[fn], acc[fm][fn], 0, 0, 0);
                    acc[fm][fn] = __builtin_amdgcn_mfma_f32_16x16x32_bf16(afl[fm], bgh[fn], acc[fm][fn], 0, 0, 0);
                    if (TERMS == 3)
                        acc[fm][fn] = __builtin_amdgcn_mfma_f32_16x16x32_bf16(afh[fm], bgl[fn], acc[fm][fn], 0, 0, 0);
                }
        }
        __syncthreads();
    }

    #pragma unroll
    for (int fm = 0; fm < FM2; ++fm)
        #pragma unroll
        for (int i = 0; i < 4; ++i) {
            const int m = m0 + wm * (BM / 2) + fm * 16 + ((lane >> 4) << 2) + i;
            #pragma unroll
            for (int fn = 0; fn < FN2; ++fn) {
                const int n = n0 + wn * (BN / 2) + fn * 16 + (lane & 15);
                float v = acc[fm][fn][i];
                if (EPI == 0) {
                    float* C = (float*)Cv;
                    if (bias) v += bias[n];
                    C[(long)m * ldc + n] = v * scale;
                } else if (EPI == 1) {
                    float* C = (float*)Cv;
                    v += (float)(255 - (m & 255)) * bias[n];
                    C[(long)m * ldc + n] = v;
                } else if (EPI == 2) {
                    unsigned short* C = (unsigned short*)Cv;
                    const float val = (v + bias[n]) * scale;
                    const unsigned short hv = f2bf(val);
                    const unsigned short lv = f2bf(val - bfbits2f(hv));
                    C[(long)m * 2048 + n] = hv;
                    C[(long)m * 2048 + 1024 + n] = lv;
                } else {
                    unsigned short* C = (unsigned short*)Cv;
                    const float val = v + bias[n];
                    C[(long)m * 1024 + n] = f2bf(val);
                }
            }
        }
}

// ---- fused q/k(suffix)/v projections, 64x64 tiles, XCD-swizzled. grid (16, 40)
__global__ __launch_bounds__(256) void qkvb_kernel(
    const unsigned short* __restrict__ apk, const unsigned short* __restrict__ wpk,
    const float* __restrict__ ipb,
    unsigned short* __restrict__ qpk, float* __restrict__ sbuf,
    unsigned short* __restrict__ vpk, float qscale)
{
    __shared__ __align__(16) unsigned char lds[4 * 64 * 128];
    const int lid = blockIdx.y * 16 + blockIdx.x;
    const int xcd = lid & 7, slot = lid >> 3;        // slot in [0,80)
    const int y = xcd * 5 + (slot >> 4);
    const int x = slot & 15;
    if (y < 8) {
        bgemm2<64, 64, 3, 2>(apk, wpk, ipb, qpk, 2048, qscale,
                             y * 64, x * 64, lds);
    } else if (y < 24) {
        bgemm2<64, 64, 3, 1>(apk + 512L * 2048, wpk + 1024L * 2048, ipb + 1024, sbuf, 1024, 1.f,
                             (y - 8) * 64, x * 64, lds);
    } else {
        bgemm2<64, 64, 2, 3>(apk + 1536L * 2048, wpk + 2048L * 2048, ipb + 2048, vpk, 1024, 1.f,
                             (y - 24) * 64, x * 64, lds);
    }
}

// ---- out projection, 32x64 tiles, 2-term, XCD-swizzled. grid 256
__global__ __launch_bounds__(256) void outprojb_kernel(
    const unsigned short* __restrict__ apk2, const unsigned short* __restrict__ wpk,
    const float* __restrict__ opb, float* __restrict__ out)
{
    __shared__ __align__(16) unsigned char lds[(2 * 32 + 64) * 128];
    const int lid = blockIdx.x;
    const int xcd = lid & 7, slot = lid >> 3;        // slot in [0,32)
    const int y = xcd * 2 + (slot >> 4);
    const int x = slot & 15;
    bgemm2<32, 64, 2, 0>(apk2, wpk + 3072L * 2048, opb, out, 1024, 1.f,
                         y * 32, x * 64, lds);
}

// ============ fused attention, 8-way q split (16 q-rows/block), 2 blocks/CU. grid 256 ====
// Wave layout: 4 waves cover 4 column-chunks (wn in [0,4)); all waves share the 16 q-rows.
// LDS: QH 4K | QL 4K | KH 16K (Vt overlay) | KL 16K | PH 8K | RED 512B | INV 64B
#define F_QH 0
#define F_QL 4096
#define F_KH 8192
#define F_KL 24576
#define F_PH 40960
#define F_RED 49152
#define F_INV 49664

__global__ __launch_bounds__(256, 2) void fused_attn_kernel(
    const unsigned short* __restrict__ qpk, const float* __restrict__ sbuf,
    const unsigned short* __restrict__ vpk, const int* __restrict__ indices,
    unsigned short* __restrict__ apk2)
{
    __shared__ __align__(16) unsigned char lds[49728];
    __shared__ int onode[256];
    // XCD swizzle: 32 slots/xcd; bh = xcd*4 + slot>>3 (K/V/sbuf locality), qq8 = slot&7
    const int lid = blockIdx.x;
    const int xcd = lid & 7, slot = lid >> 3;        // slot in [0,32)
    const int bh = xcd * 4 + (slot >> 3), qq8 = slot & 7;
    const int b = bh >> 3, h = bh & 7;
    const int t = threadIdx.x, lane = t & 63, wn = t >> 6;  // wn = wave in [0,4)
    float* red = (float*)(lds + F_RED);   // [2 phase][4 wn][16 row]
    float* inv = (float*)(lds + F_INV);   // [16]

    if (t < TK) {
        const int r0 = indices[(b * TK + t) * 2 + 0];
        const int c0 = indices[(b * TK + t) * 2 + 1];
        onode[t] = t + 2 * (c0 - r0) + 1;
    } else if (t < 256) {
        onode[t] = 255;
    }

    // ---- stage Q (16 rows): straight short8 copy from packed qpk (incl. h*128 offset)
    {
        #pragma unroll
        for (int rr = 0; rr < 2; ++rr) {
            const int chunk = rr * 256 + t;        // 512 = 16 rows x 2 planes x 16 units
            const int row = chunk >> 5;
            const int rem = chunk & 31;
            const int plane = rem >> 4, u = rem & 15;
            const int tq = qq8 * 16 + row;
            short8 v = *(const short8*)(qpk + (long)(tq * 4 + b) * 2048 + plane * 1024 + h * 128 + u * 8);
            const int byte = row * 256 + ((u ^ (row & 15)) << 4);
            *(short8*)(lds + (plane ? F_QL : F_QH) + byte) = v;
        }
    }

    f32x4 acc[4];
    #pragma unroll
    for (int nb = 0; nb < 4; ++nb)
        #pragma unroll
        for (int e = 0; e < 4; ++e) acc[nb][e] = 0.f;

    #pragma unroll
    for (int nb = 0; nb < 4; ++nb) {
        __syncthreads();
        {   // stage k~: S[node] - S[onode], split hi/lo (64 nodes x 128 cols)
            const int c4 = t & 31, r8 = t >> 5;
            const float* sb = sbuf + (long)b * 256 * 1024 + h * 128 + c4 * 4;
            #pragma unroll
            for (int rr = 0; rr < 8; ++rr) {
                const int nl = r8 + rr * 8;
                const int node = nb * 64 + nl;
                float4 f0 = *(const float4*)(sb + (long)node * 1024);
                float4 f1 = *(const float4*)(sb + (long)onode[node] * 1024);
                float4 f = make_float4(f0.x - f1.x, f0.y - f1.y, f0.z - f1.z, f0.w - f1.w);
                const unsigned short h0 = f2bf(f.x), h1 = f2bf(f.y), h2 = f2bf(f.z), h3 = f2bf(f.w);
                short4v hv, lv;
                hv[0] = (short)h0; hv[1] = (short)h1; hv[2] = (short)h2; hv[3] = (short)h3;
                lv[0] = (short)f2bf(f.x - bfbits2f(h0));
                lv[1] = (short)f2bf(f.y - bfbits2f(h1));
                lv[2] = (short)f2bf(f.z - bfbits2f(h2));
                lv[3] = (short)f2bf(f.w - bfbits2f(h3));
                const int byte = nl * 256 + ((((c4 >> 1) ^ (nl & 15)) << 4) | ((c4 & 1) << 3));
                *(short4v*)(lds + F_KH + byte) = hv;
                *(short4v*)(lds + F_KL + byte) = lv;
            }
        }
        __syncthreads();
        #pragma unroll
        for (int ks = 0; ks < 4; ++ks) {
            short8 ah, al, bh_, bl;
            {
                const int row = lane & 15;
                const int byte = row * 256 + (((ks * 4 + (lane >> 4)) ^ (row & 15)) << 4);
                ah = *(const short8*)(lds + F_QH + byte);
                al = *(const short8*)(lds + F_QL + byte);
            }
            {
                const int rown = wn * 16 + (lane & 15);
                const int byte = rown * 256 + (((ks * 4 + (lane >> 4)) ^ (rown & 15)) << 4);
                bh_ = *(const short8*)(lds + F_KH + byte);
                bl = *(const short8*)(lds + F_KL + byte);
            }
            acc[nb] = __builtin_amdgcn_mfma_f32_16x16x32_bf16(ah, bh_, acc[nb], 0, 0, 0);
            acc[nb] = __builtin_amdgcn_mfma_f32_16x16x32_bf16(al, bh_, acc[nb], 0, 0, 0);
            acc[nb] = __builtin_amdgcn_mfma_f32_16x16x32_bf16(ah, bl, acc[nb], 0, 0, 0);
        }
    }

    // ---- softmax over 256 cols (col>=255 masked); rows 16, cols split 4 waves x 16 lanes
    float pmax[4] = {-1e30f, -1e30f, -1e30f, -1e30f};
    #pragma unroll
    for (int nb = 0; nb < 4; ++nb)
        #pragma unroll
        for (int i = 0; i < 4; ++i) {
            const int col = nb * 64 + wn * 16 + (lane & 15);
            const float s = (col < TK) ? acc[nb][i] : -1e30f;
            pmax[i] = fmaxf(pmax[i], s);
        }
    #pragma unroll
    for (int off = 1; off < 16; off <<= 1)
        #pragma unroll
        for (int i = 0; i < 4; ++i) pmax[i] = fmaxf(pmax[i], __shfl_xor(pmax[i], off));
    if ((lane & 15) == 0) {
        #pragma unroll
        for (int i = 0; i < 4; ++i) {
            const int row = ((lane >> 4) << 2) + i;
            red[wn * 16 + row] = pmax[i];
        }
    }
    __syncthreads();
    float rm[4];
    #pragma unroll
    for (int i = 0; i < 4; ++i) {
        const int row = ((lane >> 4) << 2) + i;
        rm[i] = fmaxf(fmaxf(red[row], red[16 + row]), fmaxf(red[32 + row], red[48 + row]));
    }
    float psum[4] = {0.f, 0.f, 0.f, 0.f};
    #pragma unroll
    for (int nb = 0; nb < 4; ++nb)
        #pragma unroll
        for (int i = 0; i < 4; ++i) {
            const int col = nb * 64 + wn * 16 + (lane & 15);
            const int row = ((lane >> 4) << 2) + i;
            float p = 0.f;
            if (col < TK) p = __expf(acc[nb][i] - rm[i]);
            psum[i] += p;
            const unsigned short hp = f2bf(p);
            const int u = ((col >> 3) ^ ((row & 15) << 1));
            const int byte = row * 512 + (u << 4) + (col & 7) * 2;
            *(unsigned short*)(lds + F_PH + byte) = hp;
        }
    #pragma unroll
    for (int off = 1; off < 16; off <<= 1)
        #pragma unroll
        for (int i = 0; i < 4; ++i) psum[i] += __shfl_xor(psum[i], off);
    if ((lane & 15) == 0) {
        #pragma unroll
        for (int i = 0; i < 4; ++i) {
            const int row = ((lane >> 4) << 2) + i;
            red[64 + wn * 16 + row] = psum[i];
        }
    }
    __syncthreads();
    if (wn == 0 && (lane & 15) == 0) {
        #pragma unroll
        for (int i = 0; i < 4; ++i) {
            const int row = ((lane >> 4) << 2) + i;
            inv[row] = 1.f / (red[64 + row] + red[80 + row] + red[96 + row] + red[112 + row]);
        }
    }

    // ---- PV: O = P . V, 1-term. Vt staged [128 d][64 n] in KH region; wave wn owns 32 d-cols.
    f32x4 accO[2];
    #pragma unroll
    for (int fn = 0; fn < 2; ++fn)
        #pragma unroll
        for (int e = 0; e < 4; ++e) accO[fn][e] = 0.f;

    #pragma unroll
    for (int nb = 0; nb < 4; ++nb) {
        __syncthreads();
        {   // transpose-stage V (bf16 direct from vpk): Vt[d][n]
            const int c8 = t & 15, r16 = t >> 4;
            #pragma unroll
            for (int rr = 0; rr < 4; ++rr) {
                const int nl = r16 + rr * 16;
                const int node = nb * 64 + nl;
                short8 v = {0, 0, 0, 0, 0, 0, 0, 0};
                if (node < TK) v = *(const short8*)(vpk + (long)(node * 4 + b) * 1024 + h * 128 + c8 * 8);
                #pragma unroll
                for (int j = 0; j < 8; ++j) {
                    const int d = c8 * 8 + j;
                    const int byte = d * 128 + ((((nl >> 3) ^ (d & 7)) << 4) | ((nl & 7) << 1));
                    *(unsigned short*)(lds + F_KH + byte) = (unsigned short)v[j];
                }
            }
        }
        __syncthreads();
        #pragma unroll
        for (int ks = 0; ks < 2; ++ks) {
            short8 pa, vb[2];
            {
                const int row = lane & 15;
                const int u = (nb * 8 + ks * 4 + (lane >> 4)) ^ ((row & 15) << 1);
                const int byte = row * 512 + (u << 4);
                pa = *(const short8*)(lds + F_PH + byte);
            }
            #pragma unroll
            for (int fn = 0; fn < 2; ++fn) {
                const int d = wn * 32 + fn * 16 + (lane & 15);
                const int u = (ks * 4 + (lane >> 4)) ^ (d & 7);
                const int byte = d * 128 + (u << 4);
                vb[fn] = *(const short8*)(lds + F_KH + byte);
            }
            #pragma unroll
            for (int fn = 0; fn < 2; ++fn)
                accO[fn] = __builtin_amdgcn_mfma_f32_16x16x32_bf16(pa, vb[fn], accO[fn], 0, 0, 0);
        }
    }

    // ---- epilogue: normalize + write packed bf16 [hi|lo] attn rows directly
    __syncthreads();
    #pragma unroll
    for (int i = 0; i < 4; ++i) {
        const int row = ((lane >> 4) << 2) + i;
        const float iv = inv[row];
        const int arow = (qq8 * 16 + row) * 4 + b;
        #pragma unroll
        for (int fn = 0; fn < 2; ++fn) {
            const int col = h * 128 + wn * 32 + fn * 16 + (lane & 15);
            const float val = accO[fn][i] * iv;
            const unsigned short hv = f2bf(val);
            const unsigned short lv = f2bf(val - bfbits2f(hv));
            apk2[(long)arow * 2048 + col] = hv;
            apk2[(long)arow * 2048 + 1024 + col] = lv;
        }
    }
}

extern "C" void kernel_launch(void* const* d_in, const int* in_sizes, int n_in,
                              void* d_out, int out_size, void* d_ws, size_t ws_size,
                              hipStream_t stream) {
    const float* query   = (const float*)d_in[0];
    const float* key_t   = (const float*)d_in[1];
    const float* value   = (const float*)d_in[2];
    const int*   indices = (const int*)d_in[3];
    const float* ipw     = (const float*)d_in[4];
    const float* ipb     = (const float*)d_in[5];
    const float* opw     = (const float*)d_in[6];
    const float* opb     = (const float*)d_in[7];
    float* out = (float*)d_out;

    float* ws = (float*)d_ws;
    float* sbuf = ws;                                          // [1024][1024] fp32 (4 MB)
    unsigned short* qpk = (unsigned short*)(sbuf + 1048576);   // [512][2048] bf16 hi/lo
    unsigned short* vpk = qpk + 512L * 2048;                   // [1024][1024] bf16 hi
    unsigned short* apk = vpk + 1024L * 1024;                  // [2560][2048]
    unsigned short* wpk = apk + 2560L * 2048;                  // [4096][2048]
    unsigned short* apk2 = apk;                                // overlay (apk dead after qkvb)

    const float qscale = 0.08838834764831843f;  // 128^-0.5

    prep_kernel<<<dim3(2176), 256, 0, stream>>>(query, key_t, value, ipw, opw, apk, wpk);

    qkvb_kernel<<<dim3(16, 40), 256, 0, stream>>>(apk, wpk, ipb, qpk, sbuf, vpk, qscale);

    fused_attn_kernel<<<dim3(256), 256, 0, stream>>>(qpk, sbuf, vpk, indices, apk2);

    outprojb_kernel<<<dim3(256), 256, 0, stream>>>(apk2, wpk, opb, out);
}